// Round 1
// baseline (483.816 us; speedup 1.0000x reference)
//
#include <hip/hip_runtime.h>
#include <math.h>

// FeatureWeightNet: grid_sample(bilinear,border) -> group correlation (G=8) ->
// MLP(8->16->8->1) with per-batch BN stats -> sigmoid.
// R8: keep R2's proven gather kernel untouched. Rebuild the MLP/stats tail:
//  - 4 pixels/thread in stats1/stats2/final => LDS weight reads amortized 4x
//    (was ~256 ds_read/pixel => LDS-issue-bound; now VALU-bound).
//  - NO atomics: per-block partial sums written to ws; consumer kernels
//    redundantly reduce the tiny partial array (92 KB, L2-hot) in their
//    prologue. Still 5 dispatches.
//  - partials overlay featB region (dead after k_sample) => ws size unchanged.

constexpr int   Bc  = 2;
constexpr int   Cc  = 64;
constexpr int   Hc  = 256;
constexpr int   Wc  = 320;
constexpr int   NBc = 9;
constexpr int   HWc = Hc * Wc;            // 81920
constexpr int   NPIX = Bc * HWc;          // 163840
constexpr int   NPT  = Bc * NBc * HWc;    // 1474560 (= out_size)
constexpr float EPSV = 1e-5f;

constexpr int NBLK_S = NPIX / 32;         // 5120 sample blocks
constexpr int NGRP   = NPT / 1024;        // 1440 groups of 1024 pixels
constexpr int NB1    = 720;               // stats1 blocks (2 groups each)
constexpr int NB2    = 720;               // stats2 blocks
constexpr int NBF    = 720;               // final blocks

// workspace layout in float units (~45 MB, same as before)
constexpr size_t OFF_FEATB = 0;                               // NHWC bf16: NPIX*64 ushort
constexpr size_t OFF_SB    = OFF_FEATB + (size_t)NPIX * 32;   // s bf16: NPT*8 ushort
// partials overlay featB (featB is dead once k_sample has run):
constexpr size_t OFF_P1    = 0;                               // NB1*32 floats
constexpr size_t OFF_P2    = OFF_P1 + (size_t)NB1 * 32;       // NB2*16 floats

__device__ __forceinline__ unsigned short f2bf_rne(float v) {
  unsigned int u = __float_as_uint(v);
  unsigned int r = (u + 0x7fffu + ((u >> 16) & 1u)) >> 16;
  return (unsigned short)r;
}
__device__ __forceinline__ void unpack8(uint4 u, float f[8]) {
  f[0] = __uint_as_float(u.x << 16);
  f[1] = __uint_as_float(u.x & 0xffff0000u);
  f[2] = __uint_as_float(u.y << 16);
  f[3] = __uint_as_float(u.y & 0xffff0000u);
  f[4] = __uint_as_float(u.z << 16);
  f[5] = __uint_as_float(u.z & 0xffff0000u);
  f[6] = __uint_as_float(u.w << 16);
  f[7] = __uint_as_float(u.w & 0xffff0000u);
}
__device__ __forceinline__ float dot8(const float s[8], float4 wa, float4 wb) {
  return s[0] * wa.x + s[1] * wa.y + s[2] * wa.z + s[3] * wa.w +
         s[4] * wb.x + s[5] * wb.y + s[6] * wb.z + s[7] * wb.w;
}

// ---------------------------------------------------------------------------
// K0: NCHW fp32 -> NHWC bf16 transpose.
__global__ __launch_bounds__(256) void k_transpose(
    const float* __restrict__ feat, unsigned short* __restrict__ featB) {
  __shared__ float lds[64][65];
  const int tid  = threadIdx.x;
  const int b    = blockIdx.x / (HWc / 64);
  const int tile = blockIdx.x % (HWc / 64);
  const int hw0  = tile * 64;
  const int p    = tid & 63;
  const int ty   = tid >> 6;  // 0..3

  const float* src = feat + (size_t)b * Cc * HWc + hw0 + p;
#pragma unroll
  for (int c0 = 0; c0 < 64; c0 += 4) {
    lds[c0 + ty][p] = src[(size_t)(c0 + ty) * HWc];
  }
  __syncthreads();
  const int ch = tid & 63;
  unsigned short* dst = featB + ((size_t)b * HWc + hw0) * 64 + ch;
#pragma unroll
  for (int p0 = 0; p0 < 64; p0 += 4) {
    dst[(size_t)(p0 + ty) * 64] = f2bf_rne(lds[ch][p0 + ty]);
  }
}

// ---------------------------------------------------------------------------
// K1: grid sample + group correlation.  PURE gather kernel (R2 structure —
// proven 3.9 TB/s): 8 lanes per pixel, lane j owns group j, loop over 9
// neighbors, no LDS, no shuffles, no stats.  UNCHANGED.
__global__ __launch_bounds__(256) void k_sample(
    const float* __restrict__ grid, const unsigned short* __restrict__ featB,
    unsigned short* __restrict__ sOut) {
  const int tid = threadIdx.x;
  const int cid = blockIdx.x * 32 + (tid >> 3);  // pixel id in [0, NPIX)
  const int j   = tid & 7;                       // group
  const int b   = cid / HWc;
  const int hw  = cid - b * HWc;
  const int h   = hw / Wc;
  const int w   = hw - h * Wc;

  const uint4* fbAll = (const uint4*)featB;
  const uint4 ur = fbAll[(size_t)cid * 8 + j];
  float r[8];
  unpack8(ur, r);

  const uint4* fb = fbAll + (size_t)b * HWc * 8;

#pragma unroll 3
  for (int n = 0; n < NBc; ++n) {
    const size_t gi = ((((size_t)b * NBc + n) * Hc + h) * Wc + w) * 2;
    const float2 g2 = *(const float2*)(grid + gi);
    float ix = ((g2.x + 1.f) * (float)Wc - 1.f) * 0.5f;
    float iy = ((g2.y + 1.f) * (float)Hc - 1.f) * 0.5f;
    ix = fminf(fmaxf(ix, 0.f), (float)(Wc - 1));
    iy = fminf(fmaxf(iy, 0.f), (float)(Hc - 1));
    const float x0f = floorf(ix), y0f = floorf(iy);
    const float fx = ix - x0f, fy = iy - y0f;
    const int x0 = (int)x0f, y0 = (int)y0f;
    const int x1 = min(x0 + 1, Wc - 1), y1 = min(y0 + 1, Hc - 1);
    const float w00 = (1.f - fx) * (1.f - fy);
    const float w01 = fx * (1.f - fy);
    const float w10 = (1.f - fx) * fy;
    const float w11 = fx * fy;

    const uint4 u00 = fb[(size_t)(y0 * Wc + x0) * 8 + j];
    const uint4 u01 = fb[(size_t)(y0 * Wc + x1) * 8 + j];
    const uint4 u10 = fb[(size_t)(y1 * Wc + x0) * 8 + j];
    const uint4 u11 = fb[(size_t)(y1 * Wc + x1) * 8 + j];
    float a[8], c[8], d[8], e[8];
    unpack8(u00, a);
    unpack8(u01, c);
    unpack8(u10, d);
    unpack8(u11, e);

    float s = 0.f;
#pragma unroll
    for (int k = 0; k < 8; ++k) {
      s += (w00 * a[k] + w01 * c[k] + w10 * d[k] + w11 * e[k]) * r[k];
    }
    s *= 0.125f;  // mean over C/G = 8

    const size_t pt = ((size_t)b * NBc + n) * HWc + hw;
    sOut[pt * 8 + j] = f2bf_rne(s);
  }
}

// ---------------------------------------------------------------------------
// K2: stats1 — y/y^2 sums, y = w0 @ s (16 ch).  4 pixels/thread; per-block
// partials to part1[NB1][32], no atomics.
__global__ __launch_bounds__(256) void k_stats1(
    const unsigned short* __restrict__ sB, const float* __restrict__ w0,
    float* __restrict__ part1) {
  __shared__ float w0s[128];
  __shared__ float red[4 * 32];
  const int tid = threadIdx.x;
  if (tid < 128) w0s[tid] = w0[tid];
  __syncthreads();

  float sy[16], sy2[16];
#pragma unroll
  for (int c = 0; c < 16; ++c) { sy[c] = 0.f; sy2[c] = 0.f; }

  for (int g = blockIdx.x; g < NGRP; g += NB1) {
    const uint4* src = (const uint4*)sB + (size_t)g * 1024 + tid;
    float s[4][8];
#pragma unroll
    for (int i = 0; i < 4; ++i) {
      const uint4 su = src[i * 256];
      unpack8(su, s[i]);
    }
#pragma unroll
    for (int c = 0; c < 16; ++c) {
      const float4 wa = *(const float4*)(w0s + c * 8);
      const float4 wb = *(const float4*)(w0s + c * 8 + 4);
      float ay = 0.f, ay2 = 0.f;
#pragma unroll
      for (int i = 0; i < 4; ++i) {
        const float y = dot8(s[i], wa, wb);
        ay += y;
        ay2 += y * y;
      }
      sy[c] += ay;
      sy2[c] += ay2;
    }
  }
#pragma unroll
  for (int c = 0; c < 16; ++c) {
    for (int off = 32; off >= 1; off >>= 1) {
      sy[c] += __shfl_xor(sy[c], off);
      sy2[c] += __shfl_xor(sy2[c], off);
    }
  }
  const int wid = tid >> 6;
  if ((tid & 63) == 0) {
#pragma unroll
    for (int c = 0; c < 16; ++c) {
      red[wid * 32 + c] = sy[c];
      red[wid * 32 + 16 + c] = sy2[c];
    }
  }
  __syncthreads();
  if (tid < 32) {
    part1[blockIdx.x * 32 + tid] =
        red[tid] + red[32 + tid] + red[64 + tid] + red[96 + tid];
  }
}

// ---------------------------------------------------------------------------
// K3: stats2 — prologue reduces part1 (92 KB, L2-hot) -> bn1 params in-block;
// main loop 4 pixels/thread; z/z^2 partials to part2[NB2][16], no atomics.
__global__ __launch_bounds__(256) void k_stats2(
    const unsigned short* __restrict__ sB, const float* __restrict__ part1,
    const float* __restrict__ w0, const float* __restrict__ w1,
    const float* __restrict__ g0, const float* __restrict__ b0,
    float* __restrict__ part2) {
  __shared__ float w0s[128], w1ts[128], a1s[16], c1s[16];
  __shared__ float red[256];
  const int tid = threadIdx.x;
  if (tid < 128) {
    w0s[tid] = w0[tid];
    w1ts[(tid & 15) * 8 + (tid >> 4)] = w1[tid];  // w1 transposed [c][o]
  }
  {  // block-local reduction of part1 -> ymom -> a1s/c1s
    const int c = tid & 31, chk = tid >> 5;  // 8 chunks of rows
    float acc = 0.f;
    for (int r = chk; r < NB1; r += 8) acc += part1[r * 32 + c];
    red[tid] = acc;
  }
  __syncthreads();
  if (tid < 32) {
    float v = 0.f;
#pragma unroll
    for (int k = 0; k < 8; ++k) v += red[k * 32 + tid];
    red[tid] = v;
  }
  __syncthreads();
  if (tid < 16) {
    const float invN = 1.f / (float)NPT;
    const float mean = red[tid] * invN;
    const float var = red[16 + tid] * invN - mean * mean;
    const float a = g0[tid] * rsqrtf(var + EPSV);
    a1s[tid] = a;
    c1s[tid] = b0[tid] - mean * a;
  }
  __syncthreads();

  float sz[8], sz2[8];
#pragma unroll
  for (int o = 0; o < 8; ++o) { sz[o] = 0.f; sz2[o] = 0.f; }

  for (int g = blockIdx.x; g < NGRP; g += NB2) {
    const uint4* src = (const uint4*)sB + (size_t)g * 1024 + tid;
    float s[4][8];
#pragma unroll
    for (int i = 0; i < 4; ++i) {
      const uint4 su = src[i * 256];
      unpack8(su, s[i]);
    }
    float z[4][8];
#pragma unroll
    for (int i = 0; i < 4; ++i)
#pragma unroll
      for (int o = 0; o < 8; ++o) z[i][o] = 0.f;

#pragma unroll
    for (int c = 0; c < 16; ++c) {
      const float4 wa = *(const float4*)(w0s + c * 8);
      const float4 wb = *(const float4*)(w0s + c * 8 + 4);
      const float4 ta = *(const float4*)(w1ts + c * 8);
      const float4 tb = *(const float4*)(w1ts + c * 8 + 4);
      const float a1c = a1s[c], c1c = c1s[c];
#pragma unroll
      for (int i = 0; i < 4; ++i) {
        const float y = dot8(s[i], wa, wb);
        const float x = fmaxf(a1c * y + c1c, 0.f);
        z[i][0] += ta.x * x; z[i][1] += ta.y * x;
        z[i][2] += ta.z * x; z[i][3] += ta.w * x;
        z[i][4] += tb.x * x; z[i][5] += tb.y * x;
        z[i][6] += tb.z * x; z[i][7] += tb.w * x;
      }
    }
#pragma unroll
    for (int i = 0; i < 4; ++i)
#pragma unroll
      for (int o = 0; o < 8; ++o) {
        sz[o] += z[i][o];
        sz2[o] += z[i][o] * z[i][o];
      }
  }
#pragma unroll
  for (int o = 0; o < 8; ++o) {
    for (int off = 32; off >= 1; off >>= 1) {
      sz[o] += __shfl_xor(sz[o], off);
      sz2[o] += __shfl_xor(sz2[o], off);
    }
  }
  const int wid = tid >> 6;
  if ((tid & 63) == 0) {
#pragma unroll
    for (int o = 0; o < 8; ++o) {
      red[wid * 16 + o] = sz[o];
      red[wid * 16 + 8 + o] = sz2[o];
    }
  }
  __syncthreads();
  if (tid < 16) {
    part2[blockIdx.x * 16 + tid] =
        red[tid] + red[16 + tid] + red[32 + tid] + red[48 + tid];
  }
}

// ---------------------------------------------------------------------------
// K4: final — prologue reduces part1+part2 -> bn1+bn2 params in-block;
// 4 pixels/thread; full MLP + sigmoid -> out.
__global__ __launch_bounds__(256) void k_final(
    const unsigned short* __restrict__ sB, const float* __restrict__ part1,
    const float* __restrict__ part2, const float* __restrict__ w0,
    const float* __restrict__ w1, const float* __restrict__ g0,
    const float* __restrict__ b0, const float* __restrict__ g1,
    const float* __restrict__ b1, const float* __restrict__ wsW,
    const float* __restrict__ bs, float* __restrict__ out) {
  __shared__ float w0s[128], w1ts[128], a1s[16], c1s[16], a2s[8], c2s[8],
      wss[8];
  __shared__ float bss;
  __shared__ float red[256];
  const int tid = threadIdx.x;
  if (tid < 128) {
    w0s[tid] = w0[tid];
    w1ts[(tid & 15) * 8 + (tid >> 4)] = w1[tid];
  }
  if (tid >= 128 && tid < 136) wss[tid - 128] = wsW[tid - 128];
  if (tid == 136) bss = bs[0];
  {  // reduce part1 -> bn1
    const int c = tid & 31, chk = tid >> 5;
    float acc = 0.f;
    for (int r = chk; r < NB1; r += 8) acc += part1[r * 32 + c];
    red[tid] = acc;
  }
  __syncthreads();
  if (tid < 32) {
    float v = 0.f;
#pragma unroll
    for (int k = 0; k < 8; ++k) v += red[k * 32 + tid];
    red[tid] = v;
  }
  __syncthreads();
  if (tid < 16) {
    const float invN = 1.f / (float)NPT;
    const float mean = red[tid] * invN;
    const float var = red[16 + tid] * invN - mean * mean;
    const float a = g0[tid] * rsqrtf(var + EPSV);
    a1s[tid] = a;
    c1s[tid] = b0[tid] - mean * a;
  }
  __syncthreads();
  {  // reduce part2 -> bn2
    const int c = tid & 15, chk = tid >> 4;  // 16 chunks
    float acc = 0.f;
    for (int r = chk; r < NB2; r += 16) acc += part2[r * 16 + c];
    red[tid] = acc;
  }
  __syncthreads();
  if (tid < 16) {
    float v = 0.f;
#pragma unroll
    for (int k = 0; k < 16; ++k) v += red[k * 16 + tid];
    red[tid] = v;
  }
  __syncthreads();
  if (tid < 8) {
    const float invN = 1.f / (float)NPT;
    const float mean = red[tid] * invN;
    const float var = red[8 + tid] * invN - mean * mean;
    const float a = g1[tid] * rsqrtf(var + EPSV);
    a2s[tid] = a;
    c2s[tid] = b1[tid] - mean * a;
  }
  __syncthreads();

  // cache tiny epilogue params in registers
  float a2r[8], c2r[8], wsr[8];
#pragma unroll
  for (int o = 0; o < 8; ++o) {
    a2r[o] = a2s[o];
    c2r[o] = c2s[o];
    wsr[o] = wss[o];
  }
  const float bsr = bss;

  for (int g = blockIdx.x; g < NGRP; g += NBF) {
    const uint4* src = (const uint4*)sB + (size_t)g * 1024 + tid;
    float s[4][8];
#pragma unroll
    for (int i = 0; i < 4; ++i) {
      const uint4 su = src[i * 256];
      unpack8(su, s[i]);
    }
    float z[4][8];
#pragma unroll
    for (int i = 0; i < 4; ++i)
#pragma unroll
      for (int o = 0; o < 8; ++o) z[i][o] = 0.f;

#pragma unroll
    for (int c = 0; c < 16; ++c) {
      const float4 wa = *(const float4*)(w0s + c * 8);
      const float4 wb = *(const float4*)(w0s + c * 8 + 4);
      const float4 ta = *(const float4*)(w1ts + c * 8);
      const float4 tb = *(const float4*)(w1ts + c * 8 + 4);
      const float a1c = a1s[c], c1c = c1s[c];
#pragma unroll
      for (int i = 0; i < 4; ++i) {
        const float y = dot8(s[i], wa, wb);
        const float x = fmaxf(a1c * y + c1c, 0.f);
        z[i][0] += ta.x * x; z[i][1] += ta.y * x;
        z[i][2] += ta.z * x; z[i][3] += ta.w * x;
        z[i][4] += tb.x * x; z[i][5] += tb.y * x;
        z[i][6] += tb.z * x; z[i][7] += tb.w * x;
      }
    }
#pragma unroll
    for (int i = 0; i < 4; ++i) {
      float o = bsr;
#pragma unroll
      for (int oc = 0; oc < 8; ++oc) {
        const float x2 = fmaxf(a2r[oc] * z[i][oc] + c2r[oc], 0.f);
        o += wsr[oc] * x2;
      }
      out[(size_t)g * 1024 + i * 256 + tid] = 1.f / (1.f + expf(-o));
    }
  }
}

// ---------------------------------------------------------------------------
extern "C" void kernel_launch(void* const* d_in, const int* in_sizes, int n_in,
                              void* d_out, int out_size, void* d_ws,
                              size_t ws_size, hipStream_t stream) {
  const float* feat = (const float*)d_in[0];  // [2,64,256,320]
  const float* grid = (const float*)d_in[1];  // [2,2304,320,2]
  const float* w0 = (const float*)d_in[2];    // [16,8]
  const float* g0 = (const float*)d_in[3];
  const float* b0 = (const float*)d_in[4];
  const float* w1 = (const float*)d_in[5];    // [8,16]
  const float* g1 = (const float*)d_in[6];
  const float* b1 = (const float*)d_in[7];
  const float* wsW = (const float*)d_in[8];   // [1,8]
  const float* bs = (const float*)d_in[9];    // [1]
  float* out = (float*)d_out;

  float* wsf = (float*)d_ws;  // ~45 MB
  unsigned short* featB = (unsigned short*)(wsf + OFF_FEATB);
  unsigned short* sB    = (unsigned short*)(wsf + OFF_SB);
  float* part1 = wsf + OFF_P1;  // overlays featB (dead after k_sample)
  float* part2 = wsf + OFF_P2;

  k_transpose<<<Bc * (HWc / 64), 256, 0, stream>>>(feat, featB);
  k_sample<<<NBLK_S, 256, 0, stream>>>(grid, featB, sB);
  k_stats1<<<NB1, 256, 0, stream>>>(sB, w0, part1);
  k_stats2<<<NB2, 256, 0, stream>>>(sB, part1, w0, w1, g0, b0, part2);
  k_final<<<NBF, 256, 0, stream>>>(sB, part1, part2, w0, w1, g0, b0, g1, b1,
                                   wsW, bs, out);
}